// Round 5
// baseline (9693.697 us; speedup 1.0000x reference)
//
#include <hip/hip_runtime.h>

// EncoderRNN: bidirectional GRU, T=1024, B=64, H=256, V=32000, fp32.
// Round 5: (a) scan: in-lane epilogue (gate-sliced A-frags), parity-double-
// buffered h in LDS, single lgkm-only barrier/step, 1-step-ahead xg prefetch;
// (b) xg GEMM via bf16 MFMA (emb + Wih quantized to bf16 in prep).
//
// ws layout (float offsets):
//   hcar  : 0        [dir][b][j] 2*64*256 = 32768
//   pA    : 32768    scan Whh bf16 A-frags: [dir][w8][i6][kc8][lane64][jj8] = 2*196608 ush
//   pWihB : 229376   xg Wih bf16 B-frags:  [dir][kc8][nt48][lane64][jj8]   = 2*196608 ush
//   embB  : 425984   bf16 embedding table, 32000*256 = 8192000 ush
//   xg    : 4521984  two chunk buffers of Tc*64*768 floats each (f then b)

typedef __attribute__((ext_vector_type(8))) short short8;    // 8 bf16 (4 VGPRs)
typedef __attribute__((ext_vector_type(4))) float floatx4;   // 4 fp32

__device__ __forceinline__ float sigmoid_(float x) { return 1.0f / (1.0f + __expf(-x)); }
__device__ __forceinline__ float tanh_(float x)    { return 1.0f - 2.0f / (1.0f + __expf(2.0f * x)); }
__device__ __forceinline__ unsigned short f2bf(float f) {     // RNE fp32->bf16
  unsigned int u = __float_as_uint(f);
  return (unsigned short)((u + 0x7fffu + ((u >> 16) & 1u)) >> 16);
}

// ---------------- prep kernels ----------------

__global__ __launch_bounds__(256) void prep_embB(
    const float* __restrict__ emb, unsigned short* __restrict__ embB) {
  int i4 = blockIdx.x * 256 + threadIdx.x;       // 0 .. 2047999 (float4 units)
  float4 v = ((const float4*)emb)[i4];
  ushort4 o;
  o.x = f2bf(v.x); o.y = f2bf(v.y); o.z = f2bf(v.z); o.w = f2bf(v.w);
  ((ushort4*)embB)[i4] = o;
}

// Wih -> bf16 MFMA B-frags. [dir][kc][nt][lane][jj]: B[k][n]=Wih[n][k],
// n = nt*16 + (lane&15), k = kc*32 + (lane>>4)*8 + jj.
__global__ __launch_bounds__(256) void prep_packB(
    const float* __restrict__ wf, const float* __restrict__ wb,
    unsigned short* __restrict__ oB) {
  int idx = blockIdx.x * 256 + threadIdx.x;      // 0 .. 2*196608-1
  int d = idx >= 196608;
  int o = idx - d * 196608;
  int jj   = o & 7;
  int lane = (o >> 3) & 63;
  int rest = o >> 9;                             // 0..383 = kc*48 + nt
  int nt   = rest % 48;
  int kc   = rest / 48;
  int n = nt * 16 + (lane & 15);
  int k = kc * 32 + ((lane >> 4) << 3) + jj;
  const float* w = d ? wb : wf;
  oB[idx] = f2bf(w[n * 256 + k]);
}

// Whh -> bf16 MFMA A-frags, gate-sliced per wave:
// [dir][w][i][kc][lane][jj], i = g*2+u: row = g*256 + w*32 + u*16 + (lane&15),
// k = kc*32 + (lane>>4)*8 + jj.  (wave w owns j in [w*32, w*32+32) for ALL gates)
__global__ __launch_bounds__(256) void prep_packA(
    const float* __restrict__ wf, const float* __restrict__ wb,
    unsigned short* __restrict__ oA) {
  int idx = blockIdx.x * 256 + threadIdx.x;      // 0 .. 2*196608-1
  int d = idx >= 196608;
  int o = idx - d * 196608;
  int jj   = o & 7;
  int lane = (o >> 3) & 63;
  int kc   = (o >> 9) & 7;
  int rest = o >> 12;                            // 0..95 = w*6 + i
  int i = rest % 6, w = rest / 6;
  int g = i >> 1, u = i & 1;
  int row = g * 256 + w * 32 + u * 16 + (lane & 15);
  int k   = kc * 32 + ((lane >> 4) << 3) + jj;
  const float* wsrc = d ? wb : wf;
  oA[idx] = f2bf(wsrc[row * 256 + k]);
}

// ---------------- xg GEMM (bf16 MFMA) ----------------
// Block = one (sx, dir): 256 thr / 4 waves. Wave w -> m-tile w (batches
// 16w..16w+15), all 48 n-tiles. A gathered per-lane from embB; B staged
// per-kc in LDS (48 KB).
__global__ __launch_bounds__(256) void xg_gemm(
    const int* __restrict__ seq,
    const unsigned short* __restrict__ embB,
    const unsigned short* __restrict__ pWihB,
    const float* __restrict__ bih_f, const float* __restrict__ bih_b,
    float* __restrict__ xg_f, float* __restrict__ xg_b,
    int base_f, int base_b) {
  const int tid  = threadIdx.x;
  const int lane = tid & 63;
  const int w    = tid >> 6;
  const int sx   = blockIdx.x;
  const int dir  = blockIdx.y;
  const int t    = (dir ? base_b : base_f) + sx;
  const int c    = lane & 15, qq = lane >> 4;

  const float* bih = dir ? bih_b : bih_f;
  float* xgo = (dir ? xg_b : xg_f) + (size_t)sx * 64 * 768;

  // A-frags: token row for m = lane&15 of tile w; prefetch all 8 kc.
  const int tk = seq[t * 64 + w * 16 + c];
  const unsigned short* aptr = embB + (size_t)tk * 256 + qq * 8;
  short8 afr[8];
#pragma unroll
  for (int kc = 0; kc < 8; ++kc) afr[kc] = *(const short8*)(aptr + kc * 32);

  __shared__ __align__(16) float4 Bs4[3072];     // 48 KB: [nt48][lane64][jj8] bf16

  floatx4 acc[48];
#pragma unroll
  for (int nt = 0; nt < 48; ++nt) acc[nt] = (floatx4){0.f, 0.f, 0.f, 0.f};

  for (int kc = 0; kc < 8; ++kc) {
    __syncthreads();
    const float4* src = (const float4*)(pWihB + (size_t)dir * 196608 + kc * 24576);
#pragma unroll
    for (int i = 0; i < 12; ++i) Bs4[tid + i * 256] = src[tid + i * 256];
    __syncthreads();
    const short8* bsv = (const short8*)Bs4;
    short8 af = afr[kc];
#pragma unroll
    for (int nt = 0; nt < 48; ++nt)
      acc[nt] = __builtin_amdgcn_mfma_f32_16x16x32_bf16(af, bsv[nt * 64 + lane], acc[nt], 0, 0, 0);
  }

  // D: col = lane&15 (n within tile), row = qq*4+reg (m = batch within tile)
#pragma unroll
  for (int nt = 0; nt < 48; ++nt) {
    float bv = bih[nt * 16 + c];
#pragma unroll
    for (int r = 0; r < 4; ++r)
      xgo[(size_t)(w * 16 + qq * 4 + r) * 768 + nt * 16 + c] = acc[nt][r] + bv;
  }
}

// ---------------- recurrent scan ----------------
// Grid (32 pairs, 2 dirs) x 512 thr. Wave w holds, for each gate g and
// half u, tile rows g*256 + w*32 + u*16 + m  => after MFMA the 8 active
// lanes (nB<2, qq) own r,z,n for j = w*32+u*16+qq*4+r, batch b0+nB: the
// whole GRU cell is computed IN-LANE. h: fp32 in regs; bf16 parity-double-
// buffered in LDS. One lgkm-only barrier per step; xg prefetched 1 step ahead.
__global__ __launch_bounds__(512) void gru_scan(
    const int* __restrict__ lens,
    const float* __restrict__ xg_f, const float* __restrict__ xg_b,
    const unsigned short* __restrict__ pA,
    const float* __restrict__ bhh_f, const float* __restrict__ bhh_b,
    float* __restrict__ out, float* __restrict__ hcar,
    int base_f, int base_b, int Tc, int is_last, int do_add) {
  const int tid  = threadIdx.x;
  const int lane = tid & 63;
  const int wv   = tid >> 6;                     // 0..7
  const int qp   = blockIdx.x;
  const int dir  = blockIdx.y;
  const int b0   = qp * 2;

  const float* xg  = dir ? xg_b : xg_f;
  const float* bhh = dir ? bhh_b : bhh_f;
  const int len0 = lens[b0], len1 = lens[b0 + 1];
  const int lenmax = len0 > len1 ? len0 : len1;
  const int base = dir ? base_b : base_f;

  // Resident A-frags: 6 (g,u) x 8 kc x 4 VGPRs = 192 regs (AGPR-backed).
  short8 af[6][8];
  {
    const short8* pA8 = (const short8*)(pA + (size_t)dir * 196608);
#pragma unroll
    for (int i = 0; i < 6; ++i)
#pragma unroll
      for (int kc = 0; kc < 8; ++kc)
        af[i][kc] = pA8[((wv * 6 + i) * 8 + kc) * 64 + lane];
  }

  __shared__ __align__(16) unsigned short hbf[2][576];  // [par][nB*288 + j]

  const int nB = lane & 15, qq = lane >> 4;
  const bool bld = nB < 2;                       // 8 active lanes/wave
  const int bb = b0 + (nB & 1);
  const int jb[2] = {wv * 32 + qq * 4, wv * 32 + 16 + qq * 4};

  floatx4 hr[2], bR[2], bZ[2], bN[2];
  int blen = 0;
  if (bld) {
    blen = nB ? len1 : len0;
#pragma unroll
    for (int u = 0; u < 2; ++u) {
      hr[u] = *(const floatx4*)&hcar[dir * 16384 + bb * 256 + jb[u]];
      bR[u] = *(const floatx4*)&bhh[jb[u]];
      bZ[u] = *(const floatx4*)&bhh[256 + jb[u]];
      bN[u] = *(const floatx4*)&bhh[512 + jb[u]];
      ushort4 pk;
      pk.x = f2bf(hr[u][0]); pk.y = f2bf(hr[u][1]);
      pk.z = f2bf(hr[u][2]); pk.w = f2bf(hr[u][3]);
      *(ushort4*)&hbf[0][nB * 288 + jb[u]] = pk;
    }
  }
  __syncthreads();

  int s_lo, s_hi;
  if (dir == 0) { s_lo = 0; int e = lenmax - base; s_hi = e < 0 ? 0 : (e > Tc ? Tc : e); }
  else { int sk = base + Tc - lenmax; s_lo = sk < 0 ? 0 : (sk > Tc ? Tc : sk); s_hi = Tc; }

  int par = 0;
  floatx4 xc[6], oc[2];
  if (bld && s_lo < s_hi) {                      // preload first step's xg/oprev
    int t0 = dir ? (base + (Tc - 1 - s_lo)) : (base + s_lo);
    const float* xrow = xg + ((size_t)(t0 - base) * 64 + bb) * 768;
#pragma unroll
    for (int g = 0; g < 3; ++g)
#pragma unroll
      for (int u = 0; u < 2; ++u)
        xc[g * 2 + u] = *(const floatx4*)(xrow + g * 256 + jb[u]);
    if (do_add)
#pragma unroll
      for (int u = 0; u < 2; ++u)
        oc[u] = *(const floatx4*)&out[((size_t)t0 * 64 + bb) * 256 + jb[u]];
  }

  for (int s = s_lo; s < s_hi; ++s) {
    const int t = dir ? (base + (Tc - 1 - s)) : (base + s);

    // prefetch next step's xg/oprev (consumed next iteration)
    const int sn = (s + 1 < s_hi) ? s + 1 : s;
    const int tn = dir ? (base + (Tc - 1 - sn)) : (base + sn);
    floatx4 xn_[6], on_[2];
    if (bld) {
      const float* xrow = xg + ((size_t)(tn - base) * 64 + bb) * 768;
#pragma unroll
      for (int g = 0; g < 3; ++g)
#pragma unroll
        for (int u = 0; u < 2; ++u)
          xn_[g * 2 + u] = *(const floatx4*)(xrow + g * 256 + jb[u]);
      if (do_add)
#pragma unroll
        for (int u = 0; u < 2; ++u)
          on_[u] = *(const floatx4*)&out[((size_t)tn * 64 + bb) * 256 + jb[u]];
    }

    floatx4 acc[6];
#pragma unroll
    for (int i = 0; i < 6; ++i) acc[i] = (floatx4){0.f, 0.f, 0.f, 0.f};
#pragma unroll
    for (int kc = 0; kc < 8; ++kc) {
      short8 bfr = {0, 0, 0, 0, 0, 0, 0, 0};
      if (bld) bfr = *(const short8*)&hbf[par][nB * 288 + qq * 8 + kc * 32];
#pragma unroll
      for (int i = 0; i < 6; ++i)
        acc[i] = __builtin_amdgcn_mfma_f32_16x16x32_bf16(af[i][kc], bfr, acc[i], 0, 0, 0);
    }

    if (bld) {
      const bool act = t < blen;
#pragma unroll
      for (int u = 0; u < 2; ++u) {
        floatx4 hnv;
#pragma unroll
        for (int r = 0; r < 4; ++r) {
          float hv = hr[u][r];
          float rg = sigmoid_(xc[u][r]     + acc[u][r]     + bR[u][r]);
          float zg = sigmoid_(xc[2 + u][r] + acc[2 + u][r] + bZ[u][r]);
          float ng = tanh_(xc[4 + u][r] + rg * (acc[4 + u][r] + bN[u][r]));
          float hnew = (1.0f - zg) * ng + zg * hv;
          hnv[r] = act ? hnew : hv;
        }
        hr[u] = hnv;
        ushort4 pk;
        pk.x = f2bf(hnv[0]); pk.y = f2bf(hnv[1]);
        pk.z = f2bf(hnv[2]); pk.w = f2bf(hnv[3]);
        *(ushort4*)&hbf[par ^ 1][nB * 288 + jb[u]] = pk;   // always: carry h
        if (act) {
          floatx4 ov = hnv;
          if (do_add) ov += oc[u];
          *(floatx4*)&out[((size_t)t * 64 + bb) * 256 + jb[u]] = ov;
        }
      }
    }
    // LDS-only drain + barrier: out stores stay in flight (never re-read).
    asm volatile("s_waitcnt lgkmcnt(0)\n\ts_barrier" ::: "memory");
    par ^= 1;
#pragma unroll
    for (int i = 0; i < 6; ++i) xc[i] = xn_[i];
    oc[0] = on_[0]; oc[1] = on_[1];
  }

  if (bld) {
#pragma unroll
    for (int u = 0; u < 2; ++u) {
      *(floatx4*)&hcar[dir * 16384 + bb * 256 + jb[u]] = hr[u];
      if (is_last)
        *(floatx4*)&out[(size_t)1024 * 64 * 256 + (size_t)dir * 16384 + bb * 256 + jb[u]] = hr[u];
    }
  }
}

extern "C" void kernel_launch(void* const* d_in, const int* in_sizes, int n_in,
                              void* d_out, int out_size, void* d_ws, size_t ws_size,
                              hipStream_t stream) {
  const int*   seq   = (const int*)d_in[0];
  const int*   lens  = (const int*)d_in[1];
  const float* emb   = (const float*)d_in[2];
  const float* Wih_f = (const float*)d_in[3];
  const float* Whh_f = (const float*)d_in[4];
  const float* bih_f = (const float*)d_in[5];
  const float* bhh_f = (const float*)d_in[6];
  const float* Wih_b = (const float*)d_in[7];
  const float* Whh_b = (const float*)d_in[8];
  const float* bih_b = (const float*)d_in[9];
  const float* bhh_b = (const float*)d_in[10];
  float* out = (float*)d_out;
  float* ws  = (float*)d_ws;

  float*          hcar   = ws;
  unsigned short* pA     = (unsigned short*)(ws + 32768);
  unsigned short* pWihB  = (unsigned short*)(ws + 229376);
  unsigned short* embB   = (unsigned short*)(ws + 425984);
  float*          xgbase = ws + 4521984;

  // Largest Tc whose two xg chunk buffers fit in ws (C = 1024/Tc even).
  int Tc = 8;
  const int cands[7] = {512, 256, 128, 64, 32, 16, 8};
  for (int i = 0; i < 7; ++i) {
    size_t need = (4521984ull + 2ull * (size_t)cands[i] * 49152ull) * 4ull;
    if (need <= ws_size) { Tc = cands[i]; break; }
  }
  const int C = 1024 / Tc;
  float* xg_f = xgbase;
  float* xg_b = xgbase + (size_t)Tc * 49152;

  hipMemsetAsync(d_out, 0, (size_t)1024 * 64 * 256 * 4, stream);  // masked outputs stay 0
  hipMemsetAsync(hcar, 0, 32768ull * 4ull, stream);               // initial h = 0
  prep_embB<<<dim3(8000), dim3(256), 0, stream>>>(emb, embB);
  prep_packB<<<dim3(1536), dim3(256), 0, stream>>>(Wih_f, Wih_b, pWihB);
  prep_packA<<<dim3(1536), dim3(256), 0, stream>>>(Whh_f, Whh_b, pA);

  for (int c = 0; c < C; ++c) {
    int base_f = c * Tc;
    int base_b = (C - 1 - c) * Tc;               // mirrored chunk for reverse scan
    int do_add = (2 * c >= C) ? 1 : 0;           // second writer at a given t adds
    xg_gemm<<<dim3(Tc, 2), dim3(256), 0, stream>>>(
        seq, embB, pWihB, bih_f, bih_b, xg_f, xg_b, base_f, base_b);
    gru_scan<<<dim3(32, 2), dim3(512), 0, stream>>>(
        lens, xg_f, xg_b, pA, bhh_f, bhh_b, out, hcar,
        base_f, base_b, Tc, (c == C - 1) ? 1 : 0, do_add);
  }
}

// Round 6
// 2086.976 us; speedup vs baseline: 4.6449x; 4.6449x over previous
//
#include <hip/hip_runtime.h>

// EncoderRNN: bidirectional GRU, T=1024, B=64, H=256, V=32000, fp32.
// Round 6: R4 scan (persistent bf16 MFMA A-frags, 512-thread epilogue, two
// plain barriers — known 1.55 us/step) + R5 bf16-MFMA xg_gemm, plus a
// minimal one-step-ahead xg/oprev prefetch (4 scalars/thread) in the scan.
//
// ws layout (float offsets):
//   hcar  : 0        [dir][b][j] 2*64*256 = 32768
//   pA    : 32768    scan Whh bf16 A-frags [dir][tile48][kc8][lane64][jj8] = 2*196608 ush
//   pWihB : 229376   xg Wih bf16 B-frags  [dir][kc8][nt48][lane64][jj8]   = 2*196608 ush
//   embB  : 425984   bf16 embedding table, 32000*256 = 8192000 ush
//   xg    : 4521984  two chunk buffers of Tc*64*768 floats each (f then b)

typedef __attribute__((ext_vector_type(8))) short short8;    // 8 bf16 (4 VGPRs)
typedef __attribute__((ext_vector_type(4))) float floatx4;   // 4 fp32

__device__ __forceinline__ float sigmoid_(float x) { return 1.0f / (1.0f + __expf(-x)); }
__device__ __forceinline__ float tanh_(float x)    { return 1.0f - 2.0f / (1.0f + __expf(2.0f * x)); }
__device__ __forceinline__ unsigned short f2bf(float f) {     // RNE fp32->bf16
  unsigned int u = __float_as_uint(f);
  return (unsigned short)((u + 0x7fffu + ((u >> 16) & 1u)) >> 16);
}

// ---------------- prep kernels ----------------

__global__ __launch_bounds__(256) void prep_embB(
    const float* __restrict__ emb, unsigned short* __restrict__ embB) {
  int i4 = blockIdx.x * 256 + threadIdx.x;       // 0 .. 2047999 (float4 units)
  float4 v = ((const float4*)emb)[i4];
  ushort4 o;
  o.x = f2bf(v.x); o.y = f2bf(v.y); o.z = f2bf(v.z); o.w = f2bf(v.w);
  ((ushort4*)embB)[i4] = o;
}

// Wih -> bf16 MFMA B-frags. [dir][kc][nt][lane][jj]: B[k][n]=Wih[n][k],
// n = nt*16 + (lane&15), k = kc*32 + (lane>>4)*8 + jj.
__global__ __launch_bounds__(256) void prep_packB(
    const float* __restrict__ wf, const float* __restrict__ wb,
    unsigned short* __restrict__ oB) {
  int idx = blockIdx.x * 256 + threadIdx.x;      // 0 .. 2*196608-1
  int d = idx >= 196608;
  int o = idx - d * 196608;
  int jj   = o & 7;
  int lane = (o >> 3) & 63;
  int rest = o >> 9;                             // 0..383 = kc*48 + nt
  int nt   = rest % 48;
  int kc   = rest / 48;
  int n = nt * 16 + (lane & 15);
  int k = kc * 32 + ((lane >> 4) << 3) + jj;
  const float* w = d ? wb : wf;
  oB[idx] = f2bf(w[n * 256 + k]);
}

// Whh -> bf16 MFMA A-frags (R4 layout).
// pA[dir][tile(48)][kc(8)][lane(64)][jj(8)]: row = tile*16 + (lane&15),
// k = kc*32 + (lane>>4)*8 + jj.
__global__ __launch_bounds__(256) void prep_packA(
    const float* __restrict__ wf, const float* __restrict__ wb,
    unsigned short* __restrict__ oA) {
  int idx = blockIdx.x * 256 + threadIdx.x;      // 0 .. 2*196608-1
  int d = idx >= 196608;
  int o = idx - d * 196608;
  int jj   = o & 7;
  int lane = (o >> 3) & 63;
  int kc   = (o >> 9) & 7;
  int tl   = o >> 12;                            // 0..47
  int row  = tl * 16 + (lane & 15);
  int k    = kc * 32 + ((lane >> 4) << 3) + jj;
  const float* w = d ? wb : wf;
  oA[idx] = f2bf(w[row * 256 + k]);
}

// ---------------- xg GEMM (bf16 MFMA) ----------------
// Block = one (sx, dir): 256 thr / 4 waves. Wave w -> m-tile w (batches
// 16w..16w+15), all 48 n-tiles. A gathered per-lane from embB; B staged
// per-kc in LDS (48 KB).
__global__ __launch_bounds__(256) void xg_gemm(
    const int* __restrict__ seq,
    const unsigned short* __restrict__ embB,
    const unsigned short* __restrict__ pWihB,
    const float* __restrict__ bih_f, const float* __restrict__ bih_b,
    float* __restrict__ xg_f, float* __restrict__ xg_b,
    int base_f, int base_b) {
  const int tid  = threadIdx.x;
  const int lane = tid & 63;
  const int w    = tid >> 6;
  const int sx   = blockIdx.x;
  const int dir  = blockIdx.y;
  const int t    = (dir ? base_b : base_f) + sx;
  const int c    = lane & 15, qq = lane >> 4;

  const float* bih = dir ? bih_b : bih_f;
  float* xgo = (dir ? xg_b : xg_f) + (size_t)sx * 64 * 768;

  // A-frags: token row for m = lane&15 of tile w; prefetch all 8 kc.
  const int tk = seq[t * 64 + w * 16 + c];
  const unsigned short* aptr = embB + (size_t)tk * 256 + qq * 8;
  short8 afr[8];
#pragma unroll
  for (int kc = 0; kc < 8; ++kc) afr[kc] = *(const short8*)(aptr + kc * 32);

  __shared__ __align__(16) float4 Bs4[3072];     // 48 KB: [nt48][lane64][jj8] bf16

  floatx4 acc[48];
#pragma unroll
  for (int nt = 0; nt < 48; ++nt) acc[nt] = (floatx4){0.f, 0.f, 0.f, 0.f};

  for (int kc = 0; kc < 8; ++kc) {
    __syncthreads();
    const float4* src = (const float4*)(pWihB + (size_t)dir * 196608 + kc * 24576);
#pragma unroll
    for (int i = 0; i < 12; ++i) Bs4[tid + i * 256] = src[tid + i * 256];
    __syncthreads();
    const short8* bsv = (const short8*)Bs4;
    short8 af = afr[kc];
#pragma unroll
    for (int nt = 0; nt < 48; ++nt)
      acc[nt] = __builtin_amdgcn_mfma_f32_16x16x32_bf16(af, bsv[nt * 64 + lane], acc[nt], 0, 0, 0);
  }

  // D: col = lane&15 (n within tile), row = qq*4+reg (m = batch within tile)
#pragma unroll
  for (int nt = 0; nt < 48; ++nt) {
    float bv = bih[nt * 16 + c];
#pragma unroll
    for (int r = 0; r < 4; ++r)
      xgo[(size_t)(w * 16 + qq * 4 + r) * 768 + nt * 16 + c] = acc[nt][r] + bv;
  }
}

// ---------------- recurrent scan (R4 structure + 1-step-ahead prefetch) ----
// Grid (32 pairs, 2 dirs) x 512 threads. Wave w holds tiles 6w..6w+5
// (16 rows x 256 k) as A-frags in VGPRs/AGPRs. Per step:
// hbf(LDS) -> B-frags -> 48 MFMA/wave -> res(LDS) -> 512-thread epilogue.
__global__ __launch_bounds__(512, 2) void gru_scan(
    const int* __restrict__ lens,
    const float* __restrict__ xg_f, const float* __restrict__ xg_b,
    const unsigned short* __restrict__ pA,
    const float* __restrict__ bhh_f, const float* __restrict__ bhh_b,
    float* __restrict__ out, float* __restrict__ hcar,
    int base_f, int base_b, int Tc, int is_last, int do_add) {
  const int tid  = threadIdx.x;
  const int lane = tid & 63;
  const int wv   = tid >> 6;                     // 0..7
  const int qp   = blockIdx.x;                   // batch pair
  const int dir  = blockIdx.y;
  const int b0   = qp * 2;

  const float* xg  = dir ? xg_b : xg_f;
  const float* bhh = dir ? bhh_b : bhh_f;
  const int len0 = lens[b0], len1 = lens[b0 + 1];
  const int lenmax = len0 > len1 ? len0 : len1;
  const int base = dir ? base_b : base_f;

  // Resident A-fragments: 6 tiles x 8 k-chunks x 4 VGPRs = 192 regs.
  short8 af[6][8];
  {
    const short8* pA8 = (const short8*)(pA + (size_t)dir * 196608);
#pragma unroll
    for (int i = 0; i < 6; ++i)
#pragma unroll
      for (int kc = 0; kc < 8; ++kc)
        af[i][kc] = pA8[(((wv * 6 + i) * 8 + kc) << 6) + lane];
  }

  __shared__ __align__(16) unsigned short hbf[2 * 288];  // stride 288 ush (144 dw = 16 mod 32)
  __shared__ __align__(16) float res[2 * 784];           // stride 784 dw (16 mod 32)

  // Epilogue role: thread = (b = tid>>8, j = tid&255); h fp32 lives here.
  const int b  = tid >> 8;
  const int j  = tid & 255;
  const int bb = b0 + b;
  const int blen = b ? len1 : len0;
  float hreg = hcar[dir * 16384 + bb * 256 + j];
  const float bhr = bhh[j], bhz = bhh[256 + j], bhn = bhh[512 + j];
  hbf[b * 288 + j] = f2bf(hreg);
  __syncthreads();

  int s_lo, s_hi;
  if (dir == 0) { s_lo = 0; int e = lenmax - base; s_hi = e < 0 ? 0 : (e > Tc ? Tc : e); }
  else { int sk = base + Tc - lenmax; s_lo = sk < 0 ? 0 : (sk > Tc ? Tc : sk); s_hi = Tc; }

  const int nB = lane & 15, qq = lane >> 4;
  const bool bld = nB < 2;                       // 8 lanes/wave carry B data
  const unsigned short* hsrc = &hbf[nB * 288 + qq * 8];

  // Preload first step's epilogue operands (all 512 threads, coalesced).
  float xr = 0.f, xz = 0.f, xn = 0.f, oprev = 0.f;
  if (s_lo < s_hi) {
    const int t0  = dir ? (base + (Tc - 1 - s_lo)) : (base + s_lo);
    const float* xrow = xg + ((size_t)(t0 - base) * 64 + bb) * 768 + j;
    xr = xrow[0]; xz = xrow[256]; xn = xrow[512];
    if (do_add) oprev = out[((size_t)t0 * 64 + bb) * 256 + j];
  }

  for (int s = s_lo; s < s_hi; ++s) {
    const int t  = dir ? (base + (Tc - 1 - s)) : (base + s);
    const bool act = t < blen;

    // Prefetch NEXT step's operands; consumed next iteration (~full step span).
    const int sn = (s + 1 < s_hi) ? s + 1 : s;
    const int tn = dir ? (base + (Tc - 1 - sn)) : (base + sn);
    float xr2, xz2, xn2, oprev2 = 0.f;
    {
      const float* xrow = xg + ((size_t)(tn - base) * 64 + bb) * 768 + j;
      xr2 = xrow[0]; xz2 = xrow[256]; xn2 = xrow[512];
      if (do_add) oprev2 = out[((size_t)tn * 64 + bb) * 256 + j];
    }

    floatx4 acc[6];
#pragma unroll
    for (int i = 0; i < 6; ++i) acc[i] = (floatx4){0.f, 0.f, 0.f, 0.f};

#pragma unroll
    for (int kc = 0; kc < 8; ++kc) {
      short8 bfr = {0, 0, 0, 0, 0, 0, 0, 0};
      if (bld) bfr = *(const short8*)(hsrc + kc * 32);  // conflict-free masked b128
#pragma unroll
      for (int i = 0; i < 6; ++i)
        acc[i] = __builtin_amdgcn_mfma_f32_16x16x32_bf16(af[i][kc], bfr, acc[i], 0, 0, 0);
    }

    // extract: D col = lane&15 (batch), row = (lane>>4)*4 + reg  [m89-verified]
    if (bld) {
#pragma unroll
      for (int i = 0; i < 6; ++i) {
        int r0 = (wv * 6 + i) * 16 + qq * 4;
        *(floatx4*)&res[nB * 784 + r0] = acc[i];
      }
    }
    __syncthreads();

    // epilogue: all 512 threads, one cell each
    float ar = res[b * 784 + j];
    float az = res[b * 784 + 256 + j];
    float an = res[b * 784 + 512 + j];
    float r  = sigmoid_(xr + ar + bhr);
    float z  = sigmoid_(xz + az + bhz);
    float nn = tanh_(xn + r * (an + bhn));
    float hn = (1.0f - z) * nn + z * hreg;
    if (act) {
      hreg = hn;
      hbf[b * 288 + j] = f2bf(hn);
      out[((size_t)t * 64 + bb) * 256 + j] = do_add ? (oprev + hn) : hn;
    }
    __syncthreads();                             // hbf/res consistent for next step

    xr = xr2; xz = xz2; xn = xn2; oprev = oprev2;
  }

  hcar[dir * 16384 + bb * 256 + j] = hreg;
  if (is_last)
    out[(size_t)1024 * 64 * 256 + (size_t)dir * 16384 + bb * 256 + j] = hreg;
}

extern "C" void kernel_launch(void* const* d_in, const int* in_sizes, int n_in,
                              void* d_out, int out_size, void* d_ws, size_t ws_size,
                              hipStream_t stream) {
  const int*   seq   = (const int*)d_in[0];
  const int*   lens  = (const int*)d_in[1];
  const float* emb   = (const float*)d_in[2];
  const float* Wih_f = (const float*)d_in[3];
  const float* Whh_f = (const float*)d_in[4];
  const float* bih_f = (const float*)d_in[5];
  const float* bhh_f = (const float*)d_in[6];
  const float* Wih_b = (const float*)d_in[7];
  const float* Whh_b = (const float*)d_in[8];
  const float* bih_b = (const float*)d_in[9];
  const float* bhh_b = (const float*)d_in[10];
  float* out = (float*)d_out;
  float* ws  = (float*)d_ws;

  float*          hcar   = ws;
  unsigned short* pA     = (unsigned short*)(ws + 32768);
  unsigned short* pWihB  = (unsigned short*)(ws + 229376);
  unsigned short* embB   = (unsigned short*)(ws + 425984);
  float*          xgbase = ws + 4521984;

  // Largest Tc whose two xg chunk buffers fit in ws (C = 1024/Tc even).
  int Tc = 8;
  const int cands[7] = {512, 256, 128, 64, 32, 16, 8};
  for (int i = 0; i < 7; ++i) {
    size_t need = (4521984ull + 2ull * (size_t)cands[i] * 49152ull) * 4ull;
    if (need <= ws_size) { Tc = cands[i]; break; }
  }
  const int C = 1024 / Tc;
  float* xg_f = xgbase;
  float* xg_b = xgbase + (size_t)Tc * 49152;

  hipMemsetAsync(d_out, 0, (size_t)1024 * 64 * 256 * 4, stream);  // masked outputs stay 0
  hipMemsetAsync(hcar, 0, 32768ull * 4ull, stream);               // initial h = 0
  prep_embB<<<dim3(8000), dim3(256), 0, stream>>>(emb, embB);
  prep_packB<<<dim3(1536), dim3(256), 0, stream>>>(Wih_f, Wih_b, pWihB);
  prep_packA<<<dim3(1536), dim3(256), 0, stream>>>(Whh_f, Whh_b, pA);

  for (int c = 0; c < C; ++c) {
    int base_f = c * Tc;
    int base_b = (C - 1 - c) * Tc;               // mirrored chunk for reverse scan
    int do_add = (2 * c >= C) ? 1 : 0;           // second writer at a given t adds
    xg_gemm<<<dim3(Tc, 2), dim3(256), 0, stream>>>(
        seq, embB, pWihB, bih_f, bih_b, xg_f, xg_b, base_f, base_b);
    gru_scan<<<dim3(32, 2), dim3(512), 0, stream>>>(
        lens, xg_f, xg_b, pA, bhh_f, bhh_b, out, hcar,
        base_f, base_b, Tc, (c == C - 1) ? 1 : 0, do_add);
  }
}